// Round 11
// baseline (3233.674 us; speedup 1.0000x reference)
//
#include <hip/hip_runtime.h>
#include <hip/hip_bf16.h>
#include <math.h>

#define NB 32
#define NN 320
#define ND 512
#define KC 5            // columns per lane: 64 * 5 = 320
#define FINF 1e30f
#define EPS_TIE 1e-5f

// ---------------------------------------------------------------- K1: inverse norms
__global__ __launch_bounds__(64) void norm_kernel(const float* __restrict__ t,
                                                  float* __restrict__ s) {
    int row = blockIdx.x;
    const float4* p = (const float4*)(t + (size_t)row * ND);
    int tid = threadIdx.x;
    float4 a = p[tid];
    float4 b = p[tid + 64];
    float sum = a.x*a.x + a.y*a.y + a.z*a.z + a.w*a.w
              + b.x*b.x + b.y*b.y + b.z*b.z + b.w*b.w;
#pragma unroll
    for (int off = 32; off; off >>= 1) sum += __shfl_down(sum, off, 64);
    if (tid == 0) s[row] = 1.0f / fmaxf(sqrtf(sum), 1e-12f);
}

// ---------------------------------------------------------------- K2: cost = 1 - |n1 . n2|
__global__ __launch_bounds__(256) void cost_kernel(const float* __restrict__ t1,
                                                   const float* __restrict__ t2,
                                                   const float* __restrict__ s1,
                                                   const float* __restrict__ s2,
                                                   float* __restrict__ cost) {
    int b    = blockIdx.y;
    int tile = blockIdx.x;
    int bm0  = (tile / 5) * 64;
    int bn0  = (tile % 5) * 64;
    const float* A  = t1 + (size_t)b * NN * ND;
    const float* Bm = t2 + (size_t)b * NN * ND;
    float* C = cost + (size_t)b * NN * NN;

    __shared__ float As[16][64];
    __shared__ float Bs[16][64];

    int tid = threadIdx.x;
    int tx = tid & 15, ty = tid >> 4;
    int sm = tid >> 2;
    int skg = (tid & 3) * 4;

    float acc[4][4] = {};

    for (int k0 = 0; k0 < ND; k0 += 16) {
        float4 av = *(const float4*)(A  + (size_t)(bm0 + sm) * ND + k0 + skg);
        float4 bv = *(const float4*)(Bm + (size_t)(bn0 + sm) * ND + k0 + skg);
        __syncthreads();
        As[skg+0][sm] = av.x; As[skg+1][sm] = av.y; As[skg+2][sm] = av.z; As[skg+3][sm] = av.w;
        Bs[skg+0][sm] = bv.x; Bs[skg+1][sm] = bv.y; Bs[skg+2][sm] = bv.z; Bs[skg+3][sm] = bv.w;
        __syncthreads();
#pragma unroll
        for (int k = 0; k < 16; ++k) {
            float4 a4 = *(const float4*)&As[k][ty * 4];
            float4 b4 = *(const float4*)&Bs[k][tx * 4];
            float ar[4] = {a4.x, a4.y, a4.z, a4.w};
            float br[4] = {b4.x, b4.y, b4.z, b4.w};
#pragma unroll
            for (int r = 0; r < 4; ++r)
#pragma unroll
                for (int c = 0; c < 4; ++c)
                    acc[r][c] += ar[r] * br[c];
        }
    }

    float s2v[4];
#pragma unroll
    for (int c = 0; c < 4; ++c) s2v[c] = s2[b * NN + bn0 + tx * 4 + c];
#pragma unroll
    for (int r = 0; r < 4; ++r) {
        int gm = bm0 + ty * 4 + r;
        float s1v = s1[b * NN + gm];
        float4 o;
        o.x = 1.0f - fabsf(acc[r][0] * s1v * s2v[0]);
        o.y = 1.0f - fabsf(acc[r][1] * s1v * s2v[1]);
        o.z = 1.0f - fabsf(acc[r][2] * s1v * s2v[2]);
        o.w = 1.0f - fabsf(acc[r][3] * s1v * s2v[3]);
        *(float4*)(C + (size_t)gm * NN + bn0 + tx * 4) = o;
    }
}

// ---------------------------------------------------------------- f32 wave-64 min via DPP
template<int CTRL>
__device__ __forceinline__ float dpp_fmin(float x) {
    int xi = __float_as_int(x);
    int oi = __builtin_amdgcn_update_dpp(xi, xi, CTRL, 0xf, 0xf, false);
    return fminf(x, __int_as_float(oi));
}
__device__ __forceinline__ float wave_fmin_bcast(float x) {
    x = dpp_fmin<0x111>(x);   // row_shr:1
    x = dpp_fmin<0x112>(x);   // row_shr:2
    x = dpp_fmin<0x114>(x);   // row_shr:4
    x = dpp_fmin<0x118>(x);   // row_shr:8
    x = dpp_fmin<0x142>(x);   // row_bcast:15
    x = dpp_fmin<0x143>(x);   // row_bcast:31 -> lane 63 has the min
    return __int_as_float(__builtin_amdgcn_readlane(__float_as_int(x), 63));
}

// ---------------------------------------------------------------- K3: JV / Hungarian, 1 wave per batch
__global__ __launch_bounds__(64) void lsa_kernel(const float* __restrict__ cost_all,
                                                 float* __restrict__ out) {
    int b = blockIdx.x;
    const float* __restrict__ C = cost_all + (size_t)b * NN * NN;
    int t = threadIdx.x;

    __shared__ float u_lds[NN + 1];
    __shared__ int   p_lds[NN + 1];
    __shared__ int   way_lds[NN + 1];
    __shared__ int   assigned[NN + 1];

    for (int j = t; j <= NN; j += 64) {
        u_lds[j] = 0.0f; p_lds[j] = 0; way_lds[j] = 0; assigned[j] = 0;
    }
    __syncthreads();

    // Phase A: column minima -> v (feasible dual init)
    float v[KC];
#pragma unroll
    for (int k = 0; k < KC; ++k) v[k] = FINF;
#pragma unroll 4
    for (int i = 0; i < NN; ++i) {
        const float* row = C + (size_t)i * NN + t;
#pragma unroll
        for (int k = 0; k < KC; ++k) v[k] = fminf(v[k], row[64 * k]);
    }

    int preg[KC];                    // register mirror of p_lds[1..320]: lane t, reg k owns col t+1+64k
#pragma unroll
    for (int k = 0; k < KC; ++k) preg[k] = 0;

    // Phase B: u[i] = min_j (C[i][j] - v[j]); greedy-assign when argmin column free
    {
        float f[KC], fn[KC];
#pragma unroll
        for (int k = 0; k < KC; ++k) f[k] = C[t + 64 * k];
        for (int r = 0; r < NN; ++r) {
            if (r + 1 < NN) {
                const float* nrow = C + (size_t)(r + 1) * NN + t;
#pragma unroll
                for (int k = 0; k < KC; ++k) fn[k] = nrow[64 * k];
            }
            float bv = FINF; int bk = 0;
#pragma unroll
            for (int k = 0; k < KC; ++k) {
                float m = f[k] - v[k];
                if (m < bv) { bv = m; bk = k; }
            }
            float wmin = wave_fmin_bcast(bv);
            unsigned long long mask = __ballot(bv == wmin);
            int lsel = mask ? (int)__builtin_ctzll(mask) : 0;
            int jm = __builtin_amdgcn_readlane(t + 1 + (bk << 6), lsel);
            if (t == 0) u_lds[r + 1] = wmin;
            int jz = jm - 1, l2 = jz & 63, wh = jz >> 6;
            int pv = 0;
#pragma unroll
            for (int k = 0; k < KC; ++k) {
                int c = __builtin_amdgcn_readlane(preg[k], l2);
                if (wh == k) pv = c;
            }
            if (pv == 0) {
                if (t == 0) { p_lds[jm] = r + 1; assigned[r + 1] = 1; }
                if (l2 == t) {
#pragma unroll
                    for (int k = 0; k < KC; ++k) if (wh == k) preg[k] = r + 1;
                }
            }
            if (r + 1 < NN) {
#pragma unroll
                for (int k = 0; k < KC; ++k) f[k] = fn[k];
            }
        }
    }
    __syncthreads();

    // Phase B2: JV augmenting row reduction, 2 budgeted passes (R8 config)
    for (int pass = 0; pass < 2; ++pass) {
        int budget = 2 * NN;
        for (int r0 = 1; r0 <= NN; ++r0) {
            if (assigned[r0]) continue;       // uniform LDS read (fenced by barriers below)
            int i = r0;
            while (i != 0 && --budget >= 0) {
                const float* row = C + (size_t)(i - 1) * NN + t;
                float lm1 = FINF, lm2 = FINF; int bk = 0;
#pragma unroll
                for (int k = 0; k < KC; ++k) {
                    float m = row[64 * k] - v[k];
                    if (m < lm1) { lm2 = lm1; lm1 = m; bk = k; }
                    else         { lm2 = fminf(lm2, m); }
                }
                float wm1 = wave_fmin_bcast(lm1);
                unsigned long long mask = __ballot(lm1 == wm1);
                if (!mask) break;             // rail (cannot happen)
                int lsel = (int)__builtin_ctzll(mask);
                int j1 = __builtin_amdgcn_readlane(t + 1 + (bk << 6), lsel);
                float wm2 = wave_fmin_bcast((t == lsel) ? lm2 : lm1);
                float adj = wm2 - wm1;        // >= 0
                if (j1 < 1 || j1 > NN) break; // rail (cannot happen)
                int jz = j1 - 1, l2 = jz & 63, wh = jz >> 6;
                int pv = 0;
#pragma unroll
                for (int k = 0; k < KC; ++k) {
                    int c = __builtin_amdgcn_readlane(preg[k], l2);
                    if (wh == k) pv = c;
                }
                if (pv < 0 || pv > NN) pv = 0;  // rail (cannot happen)
                if (t == 0) u_lds[i] = wm2;     // feasible in both branches (adj==0 on abandon)
                if (pv == 0 || adj > 0.0f) {
                    if (t == 0) {
                        p_lds[j1] = i; assigned[i] = 1;
                        if (pv) assigned[pv] = 0;
                    }
                    if (t == l2) {
#pragma unroll
                        for (int k = 0; k < KC; ++k) if (wh == k) {
                            preg[k] = i;
                            v[k] -= adj;        // always on assign
                        }
                    }
                    i = pv;                   // displaced row continues (0 if col was free)
                } else {
                    i = 0;                    // exact tie on occupied column: leave for Phase C
                }
                __syncthreads();              // fence LDS mutations (1 wave: cannot deadlock)
            }
        }
        __syncthreads();
    }

    // Phase C: shortest augmenting path, scipy-form (duals static during each path)
    for (int r = 0; r < NN; ++r) {
        if (assigned[r + 1]) continue;          // uniform

        // Phase B3 (per path): dual ascent on free columns — creates a tight
        // arc into every free column so its D reaches the running minimum as
        // soon as its supporting row enters the tree.
#pragma unroll
        for (int k = 0; k < KC; ++k) {
            unsigned long long fm = __ballot(preg[k] == 0);
            while (fm) {
                int l = (int)__builtin_ctzll(fm);
                fm &= fm - 1;
                int col = l + (k << 6);          // 0-based free column (uniform)
                float lm = FINF;
#pragma unroll
                for (int m = 0; m < KC; ++m) {
                    int i = t + (m << 6);        // 0-based row
                    lm = fminf(lm, C[(size_t)i * NN + col] - u_lds[i + 1]);
                }
                float wmin = wave_fmin_bcast(lm);
                if (t == l) v[k] = fmaxf(v[k], wmin);   // ascent only
            }
        }

        const int i_row = r + 1;
        if (t == 0) p_lds[0] = i_row;           // virtual column 0 owner for the augment walk
        float D[KC]; bool used[KC];
#pragma unroll
        for (int k = 0; k < KC; ++k) { D[k] = FINF; used[k] = false; }
        int i0 = i_row, curj = 0;
        float Dcur = 0.0f, minVal = 0.0f;
        int j1 = 0;
        bool okpath = false;
        for (int step = 0; step <= NN; ++step) {
            const float* row = C + (size_t)(i0 - 1) * NN + t;
            float ui0 = u_lds[i0];              // broadcast read, hidden under row loads
            float f[KC];
#pragma unroll
            for (int k = 0; k < KC; ++k) f[k] = row[64 * k];
            float s = Dcur - ui0;
            float bv = FINF; int bk = 0;
#pragma unroll
            for (int k = 0; k < KC; ++k) {
                if (!used[k]) {
                    float rr = f[k] + (s - v[k]);
                    if (rr < D[k]) { D[k] = rr; way_lds[t + 1 + (k << 6)] = curj; }
                    if (D[k] < bv) { bv = D[k]; bk = k; }
                }
            }
            float wmin = wave_fmin_bcast(bv);

            // Free-tie shortcut: among columns within EPS of the minimum,
            // prefer a FREE one — popping any minimal column is valid
            // Dijkstra, and popping a free column terminates the path.
            float bvf = FINF; int bkf = 0;
#pragma unroll
            for (int k = 0; k < KC; ++k) {
                if (!used[k] && preg[k] == 0 && D[k] <= wmin + EPS_TIE) {
                    if (D[k] < bvf) { bvf = D[k]; bkf = k; }
                }
            }
            unsigned long long fmask = __ballot(bvf <= wmin + EPS_TIE);
            if (fmask) {
                int lf = (int)__builtin_ctzll(fmask);
                j1 = __builtin_amdgcn_readlane(t + 1 + (bkf << 6), lf);
                minVal = __int_as_float(__builtin_amdgcn_readlane(__float_as_int(bvf), lf));
                if (j1 >= 1 && j1 <= NN) okpath = true;
                break;
            }

            unsigned long long mask = __ballot(bv == wmin);
            int lsel = mask ? (int)__builtin_ctzll(mask) : 0;
            j1 = __builtin_amdgcn_readlane(t + 1 + (bk << 6), lsel);
            if (j1 < 1 || j1 > NN) break;        // rail -> okpath stays false
            Dcur = wmin;
            int jz = j1 - 1, l2 = jz & 63, wh = jz >> 6;
            int pv = 0;
#pragma unroll
            for (int k = 0; k < KC; ++k) {
                int c = __builtin_amdgcn_readlane(preg[k], l2);
                if (wh == k) pv = c;
            }
            if (pv <= 0 || pv > NN) { minVal = wmin; okpath = true; break; }  // sink (safety)
            {
                bool me = (l2 == t);
#pragma unroll
                for (int k = 0; k < KC; ++k) if (me && wh == k) used[k] = true;
            }
            i0 = pv; curj = j1;
        }
        if (okpath) {
            // one-shot dual updates (clamp: eps tie can make minVal - D < 0 by ~eps)
#pragma unroll
            for (int k = 0; k < KC; ++k) {
                if (used[k]) {
                    float adj = fmaxf(minVal - D[k], 0.0f);
                    v[k] -= adj;
                    u_lds[preg[k]] += adj;      // owner rows distinct: no collisions
                }
            }
            if (t == 0) {
                u_lds[i_row] += minVal;
                int j = j1;                      // augment walk (way chain acyclic, this-round only)
                int guard = NN + 1;
                while (j != 0 && --guard >= 0) { int jp = way_lds[j]; p_lds[j] = p_lds[jp]; j = jp; }
            }
        }
        __syncthreads();
#pragma unroll
        for (int k = 0; k < KC; ++k) preg[k] = p_lds[t + 1 + (k << 6)];  // refresh mirror
    }
    __syncthreads();

    // mean of matched costs (self-assign fallback keeps indices in-bounds)
    double sum = 0.0;
#pragma unroll
    for (int k = 0; k < KC; ++k) {
        int c = t + 64 * k;
        int p = p_lds[c + 1];
        if (p < 1 || p > NN) p = c + 1;
        sum += (double)C[(size_t)(p - 1) * NN + c];
    }
#pragma unroll
    for (int off = 32; off; off >>= 1) sum += __shfl_down(sum, off, 64);
    if (t == 0) out[b] = (float)(sum / (double)NN);
}

// ---------------------------------------------------------------- launch
extern "C" void kernel_launch(void* const* d_in, const int* in_sizes, int n_in,
                              void* d_out, int out_size, void* d_ws, size_t ws_size,
                              hipStream_t stream) {
    (void)in_sizes; (void)n_in; (void)out_size; (void)ws_size;
    const float* t1 = (const float*)d_in[0];
    const float* t2 = (const float*)d_in[1];
    float* out = (float*)d_out;

    float* s1   = (float*)d_ws;            // NB*NN
    float* s2   = s1 + NB * NN;            // NB*NN
    float* cost = s2 + NB * NN;            // NB*NN*NN

    norm_kernel<<<NB * NN, 64, 0, stream>>>(t1, s1);
    norm_kernel<<<NB * NN, 64, 0, stream>>>(t2, s2);
    cost_kernel<<<dim3(25, NB), 256, 0, stream>>>(t1, t2, s1, s2, cost);
    lsa_kernel<<<NB, 64, 0, stream>>>(cost, out);
}

// Round 12
// 2697.547 us; speedup vs baseline: 1.1987x; 1.1987x over previous
//
#include <hip/hip_runtime.h>
#include <hip/hip_bf16.h>
#include <math.h>

#define NB 32
#define NN 320
#define ND 512
#define KC 5            // columns per lane: 64 * 5 = 320
#define FINF 1e30f

// ---------------------------------------------------------------- K1: inverse norms
__global__ __launch_bounds__(64) void norm_kernel(const float* __restrict__ t,
                                                  float* __restrict__ s) {
    int row = blockIdx.x;
    const float4* p = (const float4*)(t + (size_t)row * ND);
    int tid = threadIdx.x;
    float4 a = p[tid];
    float4 b = p[tid + 64];
    float sum = a.x*a.x + a.y*a.y + a.z*a.z + a.w*a.w
              + b.x*b.x + b.y*b.y + b.z*b.z + b.w*b.w;
#pragma unroll
    for (int off = 32; off; off >>= 1) sum += __shfl_down(sum, off, 64);
    if (tid == 0) s[row] = 1.0f / fmaxf(sqrtf(sum), 1e-12f);
}

// ---------------------------------------------------------------- K2: cost = 1 - |n1 . n2|
// XCD-affinity: 1-D grid of NB*25 blocks; batch b = (x&7) + 8*((x>>3)&3) so all
// 25 tiles of batch b run on XCD b%8 (id%8 round-robin) — the same XCD whose L2
// lsa block b will read from. Working set 4 batches x 409KB = 1.6MB < 4MB L2.
__global__ __launch_bounds__(256) void cost_kernel(const float* __restrict__ t1,
                                                   const float* __restrict__ t2,
                                                   const float* __restrict__ s1,
                                                   const float* __restrict__ s2,
                                                   float* __restrict__ cost) {
    int x    = blockIdx.x;
    int b    = (x & 7) + 8 * ((x >> 3) & 3);
    int tile = x >> 5;
    int bm0  = (tile / 5) * 64;
    int bn0  = (tile % 5) * 64;
    const float* A  = t1 + (size_t)b * NN * ND;
    const float* Bm = t2 + (size_t)b * NN * ND;
    float* C = cost + (size_t)b * NN * NN;

    __shared__ float As[16][64];
    __shared__ float Bs[16][64];

    int tid = threadIdx.x;
    int tx = tid & 15, ty = tid >> 4;
    int sm = tid >> 2;
    int skg = (tid & 3) * 4;

    float acc[4][4] = {};

    for (int k0 = 0; k0 < ND; k0 += 16) {
        float4 av = *(const float4*)(A  + (size_t)(bm0 + sm) * ND + k0 + skg);
        float4 bv = *(const float4*)(Bm + (size_t)(bn0 + sm) * ND + k0 + skg);
        __syncthreads();
        As[skg+0][sm] = av.x; As[skg+1][sm] = av.y; As[skg+2][sm] = av.z; As[skg+3][sm] = av.w;
        Bs[skg+0][sm] = bv.x; Bs[skg+1][sm] = bv.y; Bs[skg+2][sm] = bv.z; Bs[skg+3][sm] = bv.w;
        __syncthreads();
#pragma unroll
        for (int k = 0; k < 16; ++k) {
            float4 a4 = *(const float4*)&As[k][ty * 4];
            float4 b4 = *(const float4*)&Bs[k][tx * 4];
            float ar[4] = {a4.x, a4.y, a4.z, a4.w};
            float br[4] = {b4.x, b4.y, b4.z, b4.w};
#pragma unroll
            for (int r = 0; r < 4; ++r)
#pragma unroll
                for (int c = 0; c < 4; ++c)
                    acc[r][c] += ar[r] * br[c];
        }
    }

    float s2v[4];
#pragma unroll
    for (int c = 0; c < 4; ++c) s2v[c] = s2[b * NN + bn0 + tx * 4 + c];
#pragma unroll
    for (int r = 0; r < 4; ++r) {
        int gm = bm0 + ty * 4 + r;
        float s1v = s1[b * NN + gm];
        float4 o;
        o.x = 1.0f - fabsf(acc[r][0] * s1v * s2v[0]);
        o.y = 1.0f - fabsf(acc[r][1] * s1v * s2v[1]);
        o.z = 1.0f - fabsf(acc[r][2] * s1v * s2v[2]);
        o.w = 1.0f - fabsf(acc[r][3] * s1v * s2v[3]);
        *(float4*)(C + (size_t)gm * NN + bn0 + tx * 4) = o;
    }
}

// ---------------------------------------------------------------- f32 wave-64 min via DPP
template<int CTRL>
__device__ __forceinline__ float dpp_fmin(float x) {
    int xi = __float_as_int(x);
    int oi = __builtin_amdgcn_update_dpp(xi, xi, CTRL, 0xf, 0xf, false);
    return fminf(x, __int_as_float(oi));
}
__device__ __forceinline__ float wave_fmin_bcast(float x) {
    x = dpp_fmin<0x111>(x);   // row_shr:1
    x = dpp_fmin<0x112>(x);   // row_shr:2
    x = dpp_fmin<0x114>(x);   // row_shr:4
    x = dpp_fmin<0x118>(x);   // row_shr:8
    x = dpp_fmin<0x142>(x);   // row_bcast:15
    x = dpp_fmin<0x143>(x);   // row_bcast:31 -> lane 63 has the min
    return __int_as_float(__builtin_amdgcn_readlane(__float_as_int(x), 63));
}

// select preg[bk] without LDS / scratch (4 cndmasks, off the critical chain)
__device__ __forceinline__ int sel_owner(const int* preg, int bk) {
    int ow = preg[0];
#pragma unroll
    for (int k = 1; k < KC; ++k) if (bk == k) ow = preg[k];
    return ow;
}

// ---------------------------------------------------------------- K3: JV / Hungarian, 1 wave per batch
__global__ __launch_bounds__(64) void lsa_kernel(const float* __restrict__ cost_all,
                                                 float* __restrict__ out) {
    int b = blockIdx.x;
    const float* __restrict__ C = cost_all + (size_t)b * NN * NN;
    int t = threadIdx.x;

    __shared__ float u_lds[NN + 1];
    __shared__ int   p_lds[NN + 1];
    __shared__ int   way_lds[NN + 1];
    __shared__ int   assigned[NN + 1];

    for (int j = t; j <= NN; j += 64) {
        u_lds[j] = 0.0f; p_lds[j] = 0; way_lds[j] = 0; assigned[j] = 0;
    }
    __syncthreads();

    // Phase A: column minima -> v (feasible dual init)
    float v[KC];
#pragma unroll
    for (int k = 0; k < KC; ++k) v[k] = FINF;
#pragma unroll 4
    for (int i = 0; i < NN; ++i) {
        const float* row = C + (size_t)i * NN + t;
#pragma unroll
        for (int k = 0; k < KC; ++k) v[k] = fminf(v[k], row[64 * k]);
    }

    int preg[KC];                    // register mirror of p_lds[1..320]: lane t, reg k owns col t+1+64k
#pragma unroll
    for (int k = 0; k < KC; ++k) preg[k] = 0;

    // Phase B: u[i] = min_j (C[i][j] - v[j]); greedy-assign when argmin column free
    {
        float f[KC], fn[KC];
#pragma unroll
        for (int k = 0; k < KC; ++k) f[k] = C[t + 64 * k];
        for (int r = 0; r < NN; ++r) {
            if (r + 1 < NN) {
                const float* nrow = C + (size_t)(r + 1) * NN + t;
#pragma unroll
                for (int k = 0; k < KC; ++k) fn[k] = nrow[64 * k];
            }
            float bv = FINF; int bk = 0;
#pragma unroll
            for (int k = 0; k < KC; ++k) {
                float m = f[k] - v[k];
                if (m < bv) { bv = m; bk = k; }
            }
            int ow = sel_owner(preg, bk);          // lane's best column's owner
            float wmin = wave_fmin_bcast(bv);
            unsigned long long mask = __ballot(bv == wmin);
            int lsel = mask ? (int)__builtin_ctzll(mask) : 0;
            int jm = __builtin_amdgcn_readlane(t + 1 + (bk << 6), lsel);
            int pv = __builtin_amdgcn_readlane(ow, lsel);
            if (t == 0) u_lds[r + 1] = wmin;
            int jz = jm - 1, l2 = jz & 63, wh = jz >> 6;
            if (pv == 0) {
                if (t == 0) { p_lds[jm] = r + 1; assigned[r + 1] = 1; }
                if (l2 == t) {
#pragma unroll
                    for (int k = 0; k < KC; ++k) if (wh == k) preg[k] = r + 1;
                }
            }
            if (r + 1 < NN) {
#pragma unroll
                for (int k = 0; k < KC; ++k) f[k] = fn[k];
            }
        }
    }
    __syncthreads();

    // Phase B2: JV augmenting row reduction, 2 budgeted passes (R8 config — best known)
    for (int pass = 0; pass < 2; ++pass) {
        int budget = 2 * NN;
        for (int r0 = 1; r0 <= NN; ++r0) {
            if (assigned[r0]) continue;       // uniform LDS read (fenced by barriers below)
            int i = r0;
            while (i != 0 && --budget >= 0) {
                const float* row = C + (size_t)(i - 1) * NN + t;
                float lm1 = FINF, lm2 = FINF; int bk = 0;
#pragma unroll
                for (int k = 0; k < KC; ++k) {
                    float m = row[64 * k] - v[k];
                    if (m < lm1) { lm2 = lm1; lm1 = m; bk = k; }
                    else         { lm2 = fminf(lm2, m); }
                }
                int ow = sel_owner(preg, bk);
                float wm1 = wave_fmin_bcast(lm1);
                unsigned long long mask = __ballot(lm1 == wm1);
                if (!mask) break;             // rail (cannot happen)
                int lsel = (int)__builtin_ctzll(mask);
                int j1 = __builtin_amdgcn_readlane(t + 1 + (bk << 6), lsel);
                int pv = __builtin_amdgcn_readlane(ow, lsel);
                float wm2 = wave_fmin_bcast((t == lsel) ? lm2 : lm1);
                float adj = wm2 - wm1;        // >= 0
                if (j1 < 1 || j1 > NN) break; // rail (cannot happen)
                if (pv < 0 || pv > NN) pv = 0;  // rail (cannot happen)
                int jz = j1 - 1, l2 = jz & 63, wh = jz >> 6;
                if (t == 0) u_lds[i] = wm2;     // feasible in both branches (adj==0 on abandon)
                if (pv == 0 || adj > 0.0f) {
                    if (t == 0) {
                        p_lds[j1] = i; assigned[i] = 1;
                        if (pv) assigned[pv] = 0;
                    }
                    if (t == l2) {
#pragma unroll
                        for (int k = 0; k < KC; ++k) if (wh == k) {
                            preg[k] = i;
                            v[k] -= adj;        // always on assign
                        }
                    }
                    i = pv;                   // displaced row continues (0 if col was free)
                } else {
                    i = 0;                    // exact tie on occupied column: leave for Phase C
                }
                __syncthreads();              // fence LDS mutations (1 wave: cannot deadlock)
            }
        }
        __syncthreads();
    }

    // Phase C: shortest augmenting path, scipy-form (duals static during each path)
    for (int r = 0; r < NN; ++r) {
        if (assigned[r + 1]) continue;          // uniform
        const int i_row = r + 1;
        if (t == 0) p_lds[0] = i_row;           // virtual column 0 owner for the augment walk
        float D[KC]; bool used[KC];
#pragma unroll
        for (int k = 0; k < KC; ++k) { D[k] = FINF; used[k] = false; }
        int i0 = i_row, curj = 0;
        float Dcur = 0.0f, minVal = 0.0f;
        int j1 = 0;
        bool okpath = false;
        for (int step = 0; step <= NN; ++step) {
            const float* row = C + (size_t)(i0 - 1) * NN + t;
            float ui0 = u_lds[i0];              // broadcast read, hidden under row loads
            float f[KC];
#pragma unroll
            for (int k = 0; k < KC; ++k) f[k] = row[64 * k];
            float s = Dcur - ui0;
            float bv = FINF; int bk = 0;
#pragma unroll
            for (int k = 0; k < KC; ++k) {
                if (!used[k]) {
                    float rr = f[k] + (s - v[k]);
                    if (rr < D[k]) { D[k] = rr; way_lds[t + 1 + (k << 6)] = curj; }
                    if (D[k] < bv) { bv = D[k]; bk = k; }
                }
            }
            int ow = sel_owner(preg, bk);        // off critical chain
            float wmin = wave_fmin_bcast(bv);
            unsigned long long mask = __ballot(bv == wmin);
            int lsel = mask ? (int)__builtin_ctzll(mask) : 0;
            j1 = __builtin_amdgcn_readlane(t + 1 + (bk << 6), lsel);
            int pv = __builtin_amdgcn_readlane(ow, lsel);
            if (j1 < 1 || j1 > NN) break;        // rail -> okpath stays false
            Dcur = wmin;
            if (pv <= 0 || pv > NN) { minVal = wmin; okpath = true; break; }  // sink
            {
                int jz = j1 - 1, l2 = jz & 63, wh = jz >> 6;
                bool me = (l2 == t);
#pragma unroll
                for (int k = 0; k < KC; ++k) if (me && wh == k) used[k] = true;
            }
            i0 = pv; curj = j1;
        }
        if (okpath) {
            // one-shot dual updates
#pragma unroll
            for (int k = 0; k < KC; ++k) {
                if (used[k]) {
                    float adj = minVal - D[k];
                    v[k] -= adj;
                    u_lds[preg[k]] += adj;      // owner rows distinct: no collisions
                }
            }
            if (t == 0) {
                u_lds[i_row] += minVal;
                int j = j1;                      // augment walk (way chain acyclic, this-round only)
                int guard = NN + 1;
                while (j != 0 && --guard >= 0) { int jp = way_lds[j]; p_lds[j] = p_lds[jp]; j = jp; }
            }
        }
        __syncthreads();
#pragma unroll
        for (int k = 0; k < KC; ++k) preg[k] = p_lds[t + 1 + (k << 6)];  // refresh mirror
    }
    __syncthreads();

    // mean of matched costs (self-assign fallback keeps indices in-bounds)
    double sum = 0.0;
#pragma unroll
    for (int k = 0; k < KC; ++k) {
        int c = t + 64 * k;
        int p = p_lds[c + 1];
        if (p < 1 || p > NN) p = c + 1;
        sum += (double)C[(size_t)(p - 1) * NN + c];
    }
#pragma unroll
    for (int off = 32; off; off >>= 1) sum += __shfl_down(sum, off, 64);
    if (t == 0) out[b] = (float)(sum / (double)NN);
}

// ---------------------------------------------------------------- launch
extern "C" void kernel_launch(void* const* d_in, const int* in_sizes, int n_in,
                              void* d_out, int out_size, void* d_ws, size_t ws_size,
                              hipStream_t stream) {
    (void)in_sizes; (void)n_in; (void)out_size; (void)ws_size;
    const float* t1 = (const float*)d_in[0];
    const float* t2 = (const float*)d_in[1];
    float* out = (float*)d_out;

    float* s1   = (float*)d_ws;            // NB*NN
    float* s2   = s1 + NB * NN;            // NB*NN
    float* cost = s2 + NB * NN;            // NB*NN*NN

    norm_kernel<<<NB * NN, 64, 0, stream>>>(t1, s1);
    norm_kernel<<<NB * NN, 64, 0, stream>>>(t2, s2);
    cost_kernel<<<dim3(NB * 25), 256, 0, stream>>>(t1, t2, s1, s2, cost);
    lsa_kernel<<<NB, 64, 0, stream>>>(cost, out);
}